// Round 12
// baseline (130.225 us; speedup 1.0000x reference)
//
#include <hip/hip_runtime.h>

#define NW 32
#define BATCH 2048
#define BIGF 1e9f

// One DPP u32-min step (row_shr within 16-lane rows). bound_ctrl=false:
// invalid-source lanes keep old value = min identity.
template <int CTRL>
__device__ __forceinline__ unsigned dpp_umin_step(unsigned x) {
    unsigned t = (unsigned)__builtin_amdgcn_update_dpp((int)x, (int)x, CTRL, 0xF, 0xF, false);
    return t < x ? t : x;
}

// Packed-key min over lanes 0..31 (others must hold ~0u): 4 DPP row_shr steps
// leave min(0..15) at lane 15, min(16..31) at lane 31; merge as scalars.
__device__ __forceinline__ unsigned wave_umin32_key(unsigned red) {
    red = dpp_umin_step<0x111>(red);   // row_shr:1
    red = dpp_umin_step<0x112>(red);   // row_shr:2
    red = dpp_umin_step<0x114>(red);   // row_shr:4
    red = dpp_umin_step<0x118>(red);   // row_shr:8
    unsigned kA = (unsigned)__builtin_amdgcn_readlane((int)red, 15);
    unsigned kB = (unsigned)__builtin_amdgcn_readlane((int)red, 31);
    return kA < kB ? kA : kB;
}

__device__ __forceinline__ float readlane_f(float v, int lane) {
    return __int_as_float(__builtin_amdgcn_readlane(__float_as_int(v), lane));
}

__global__ __launch_bounds__(64) void floorplan_hungarian_kernel(
    const float* __restrict__ params_true,
    const float* __restrict__ params_pred,
    float* __restrict__ out)
{
    const int b    = blockIdx.x;
    const int lane = threadIdx.x;           // 0..63, one full wave

    __shared__ float cost[NW][NW + 1];      // padded rows: conflict-free
    __shared__ float featT[NW][9];
    __shared__ float featP[NW][9];
    __shared__ int   rw[NW];                // CR: winning column per row

    // ---------------- Phase 1: per-wall features (1 wall per lane) -------------
    {
        const float* src = (lane < NW)
            ? (params_true + ((size_t)b * NW + lane) * 6)
            : (params_pred + ((size_t)b * NW + (lane - NW)) * 6);
        float sx = src[0], sy = src[1], ex = src[2], ey = src[3];
        float w  = src[4], prob = src[5];

        float dx = ex - sx, dy = ey - sy;
        float cx = (sx + ex) * 0.5f, cy = (sy + ey) * 0.5f;
        float len = sqrtf(dx * dx + dy * dy);
        float area = len * w;

        float smaller = fminf(w, len), bigger = fmaxf(w, len);
        float sr = (bigger > 0.0f) ? (smaller / bigger) : 0.0f;

        float px = dy, py = -dx;
        float pd = len;
        if (pd > 0.0f) { px /= pd; py /= pd; }
        px *= w * 0.5f; py *= w * 0.5f;
        float right = fmaxf(fmaxf(sx + px, sx - px), fmaxf(ex + px, ex - px));
        float top   = fmaxf(fmaxf(sy + py, sy - py), fmaxf(ey + py, ey - py));
        float bbw = fabsf((right - cx) * 2.0f);
        float bbh = fabsf((top   - cy) * 2.0f);
        float bba = bbw * bbh;
        float ar  = (bba > 0.001f) ? (area / bba) : 1.0f;

        float* f = (lane < NW) ? featT[lane] : featP[lane - NW];
        f[0] = cx;  f[1] = cy;  f[2] = area; f[3] = sr;
        f[4] = ar;  f[5] = bbw; f[6] = bbh;  f[7] = prob;
    }
    if (lane < NW) rw[lane] = 64;           // CR winner init
    __syncthreads();

    // ------- Phase 2: 32x32 cost matrix + fused column-min (CR part 1) --------
    float cmin = BIGF; int cargmin = 0;
    for (int e = lane; e < NW * NW; e += 64) {
        int i = e >> 5, j = e & 31;
        float dcx = featT[i][0] - featP[j][0];
        float dcy = featT[i][1] - featP[j][1];
        float center_d = dcx * dcx + dcy * dcy;
        float da = featT[i][2] - featP[j][2];   float area_d  = da * da;
        float ds = featT[i][3] - featP[j][3];   float lwr_d   = ds * ds;
        float dr = featT[i][4] - featP[j][4];   float rot_d   = dr * dr;
        float dxw = featT[i][5] - featP[j][5];  float horiz_d = dxw * dxw;
        float dyh = featT[i][6] - featP[j][6];  float vert_d  = dyh * dyh;
        float probt = featT[i][7], probp = featP[j][7];
        float dp = probt - probp;               float prob_d  = dp * dp;
        float param_d = area_d + center_d + rot_d + horiz_d + vert_d + lwr_d;
        float val = 10.0f * prob_d + param_d * probt;
        cost[i][j] = val;
        if (val < cmin) { cmin = val; cargmin = i; }   // rows ascending: first-min
    }
    {
        float om = __shfl_xor(cmin, 32);
        int   oi = __shfl_xor(cargmin, 32);
        if (om < cmin || (om == cmin && oi < cargmin)) { cmin = om; cargmin = oi; }
    }
    __syncthreads();

    // --------- CR part 2: deterministic unique-argmin greedy assignment --------
    if (lane < NW) atomicMin(&rw[cargmin], lane);
    __syncthreads();

    const bool isCol = lane < NW;
    const int  col   = lane & 31;
    float v_col   = isCol ? cmin : 0.0f;    // v = column min (feasible duals)
    float u_row   = 0.0f;
    int   win     = isCol ? rw[lane] : 64;
    int   col4row = (isCol && win < 64) ? win : -1;
    int   row4col = (isCol && rw[cargmin] == lane) ? cargmin : -1;
    __syncthreads();

    unsigned rem      = (unsigned)(__ballot(isCol && col4row < 0) & 0xffffffffull);
    unsigned freeCols = (unsigned)(__ballot(isCol && row4col < 0) & 0xffffffffull);

    // ------- Greedy free-row pass (ART-lite): u_i = min slack; assign if -------
    // the argmin column is free (edge tight, duals stay feasible).
    {
        unsigned g = rem;
        while (g != 0) {
            int i = __ffs(g) - 1;
            g &= (g - 1);
            float cij = cost[i][col];
            float slack = cij - v_col;                     // >= 0 (v = colmin)
            unsigned key = isCol
                ? ((__float_as_uint(slack) & 0xFFFFFFE0u) | (unsigned)col)
                : 0xFFFFFFFFu;
            unsigned kmin = wave_umin32_key(key);
            int   j1 = (int)(kmin & 31u);
            float m1 = __uint_as_float(kmin & 0xFFFFFFE0u);
            if (lane == i) u_row = m1;                     // tighten dual (feasible)
            if ((freeCols >> j1) & 1u) {                   // assign only if free
                if (lane == j1) row4col = i;
                if (lane == i)  col4row = j1;
                freeCols &= ~(1u << j1);
                rem      &= ~(1u << i);
            }
        }
    }

    // ---------------- SAP: shortest augmenting path for leftover rows ----------
    {
        while (rem != 0) {
            int i0 = __ffs(rem) - 1;
            rem &= (rem - 1);

            bool     SCb     = !isCol;
            unsigned spcKey  = 0xFFFFFFFFu;    // (quantized slack | j), frozen at SC
            int      pathReg = 0;
            unsigned srMask  = 1u << i0;
            float    minValF = 0.0f;
            int      i = i0;
            int      sink;

            // first row: direct prefetch + folded scalar delta
            float cij    = cost[i][col];
            float sDelta = 0.0f - readlane_f(u_row, i);    // minVal(0) - u[i0]
            while (true) {
                // slack = (cij - v_col) + (minVal - u_i); clamp >=0 so the bit
                // pattern is order-monotone for the packed-key u32 min.
                float slack = fmaxf((cij - v_col) + sDelta, 0.0f);
                unsigned key = (__float_as_uint(slack) & 0xFFFFFFE0u) | (unsigned)col;
                unsigned old = spcKey;
                unsigned mn  = key < spcKey ? key : spcKey;
                spcKey = SCb ? spcKey : mn;                    // freeze when SC
                pathReg = (spcKey != old) ? i : pathReg;       // source row of best
                unsigned red = SCb ? 0xFFFFFFFFu : spcKey;

                red = dpp_umin_step<0x111>(red);               // row_shr:1
                red = dpp_umin_step<0x112>(red);               // row_shr:2
                red = dpp_umin_step<0x114>(red);               // row_shr:4
                red = dpp_umin_step<0x118>(red);               // row_shr:8
                // Two group winners; speculatively prefetch BOTH candidate rows
                // before the scalar merge, so the ds_read issues ~25 cy earlier.
                unsigned kA = (unsigned)__builtin_amdgcn_readlane((int)red, 15);
                unsigned kB = (unsigned)__builtin_amdgcn_readlane((int)red, 31);
                int jA = (int)(kA & 31u), jB = (int)(kB & 31u);
                int rA = __builtin_amdgcn_readlane(row4col, jA);
                int rB = __builtin_amdgcn_readlane(row4col, jB);
                int rAc = rA < 0 ? 0 : rA, rBc = rB < 0 ? 0 : rB;
                float cA = cost[rAc][col];                     // speculative issue
                float cB = cost[rBc][col];                     // speculative issue

                bool awin = kA <= kB;                          // scalar merge
                unsigned kmin = awin ? kA : kB;
                int   j = awin ? jA : jB;
                int   r = awin ? rA : rB;
                minValF = __uint_as_float(kmin & 0xFFFFFFE0u);
                SCb = SCb || (lane == j);
                if ((freeCols >> j) & 1u) { sink = j; break; }
                i = r;
                srMask |= (1u << i);
                float u_i = readlane_f(u_row, i);
                sDelta = minValF - u_i;                        // folded scalar
                cij = awin ? cA : cB;                          // winner's row
            }

            // dual updates (spc recovered from frozen keys, quantized)
            {
                float spcF = __uint_as_float(spcKey & 0xFFFFFFE0u);
                int gidx = (col4row < 0) ? 0 : col4row;
                float spc_at_c4r = __shfl(spcF, gidx);
                bool in_SR = isCol && ((srMask >> col) & 1u);
                if (lane == i0)              u_row += minValF;
                else if (in_SR)              u_row += minValF - spc_at_c4r;
                if (isCol && SCb)            v_col -= (minValF - spcF);
            }

            // augment along path
            {
                int j = sink;
                freeCols &= ~(1u << sink);
                while (true) {
                    int ii = __builtin_amdgcn_readlane(pathReg, j);
                    if (lane == j) row4col = ii;
                    int j_next = __builtin_amdgcn_readlane(col4row, ii);
                    if (lane == ii) col4row = j;
                    if (ii == i0) break;
                    j = j_next;
                }
            }
        }
    }

    // ---------------- Loss = sum of assigned edge costs ------------------------
    float myedge = (isCol && col4row >= 0) ? cost[lane][col4row] : 0.0f;
    #pragma unroll
    for (int off = 32; off >= 1; off >>= 1)
        myedge += __shfl_xor(myedge, off);
    if (lane == 0) out[b] = myedge;
}

extern "C" void kernel_launch(void* const* d_in, const int* in_sizes, int n_in,
                              void* d_out, int out_size, void* d_ws, size_t ws_size,
                              hipStream_t stream) {
    const float* params_true = (const float*)d_in[0];
    const float* params_pred = (const float*)d_in[1];
    float* out = (float*)d_out;
    floorplan_hungarian_kernel<<<BATCH, 64, 0, stream>>>(params_true, params_pred, out);
}

// Round 13
// 119.953 us; speedup vs baseline: 1.0856x; 1.0856x over previous
//
#include <hip/hip_runtime.h>

#define NW 32
#define BATCH 2048
#define BIGF 1e9f

// One DPP u32-min step (row_shr within 16-lane rows). bound_ctrl=false:
// invalid-source lanes keep old value = min identity.
template <int CTRL>
__device__ __forceinline__ unsigned dpp_umin_step(unsigned x) {
    unsigned t = (unsigned)__builtin_amdgcn_update_dpp((int)x, (int)x, CTRL, 0xF, 0xF, false);
    return t < x ? t : x;
}

// Packed-key min over lanes 0..31 (others must hold ~0u): 4 DPP row_shr steps
// leave min(0..15) at lane 15, min(16..31) at lane 31; merge as scalars.
__device__ __forceinline__ unsigned wave_umin32_key(unsigned red) {
    red = dpp_umin_step<0x111>(red);   // row_shr:1
    red = dpp_umin_step<0x112>(red);   // row_shr:2
    red = dpp_umin_step<0x114>(red);   // row_shr:4
    red = dpp_umin_step<0x118>(red);   // row_shr:8
    unsigned kA = (unsigned)__builtin_amdgcn_readlane((int)red, 15);
    unsigned kB = (unsigned)__builtin_amdgcn_readlane((int)red, 31);
    return kA < kB ? kA : kB;
}

__device__ __forceinline__ float readlane_f(float v, int lane) {
    return __int_as_float(__builtin_amdgcn_readlane(__float_as_int(v), lane));
}

__global__ __launch_bounds__(64) void floorplan_hungarian_kernel(
    const float* __restrict__ params_true,
    const float* __restrict__ params_pred,
    float* __restrict__ out)
{
    const int b    = blockIdx.x;
    const int lane = threadIdx.x;           // 0..63, one full wave

    __shared__ float cost[NW][NW + 1];      // padded rows: conflict-free
    __shared__ float featT[NW][9];
    __shared__ float featP[NW][9];
    __shared__ int   rw[NW];                // CR: winning column per row

    // ---------------- Phase 1: per-wall features (1 wall per lane) -------------
    {
        const float* src = (lane < NW)
            ? (params_true + ((size_t)b * NW + lane) * 6)
            : (params_pred + ((size_t)b * NW + (lane - NW)) * 6);
        float sx = src[0], sy = src[1], ex = src[2], ey = src[3];
        float w  = src[4], prob = src[5];

        float dx = ex - sx, dy = ey - sy;
        float cx = (sx + ex) * 0.5f, cy = (sy + ey) * 0.5f;
        float len = sqrtf(dx * dx + dy * dy);
        float area = len * w;

        float smaller = fminf(w, len), bigger = fmaxf(w, len);
        float sr = (bigger > 0.0f) ? (smaller / bigger) : 0.0f;

        float px = dy, py = -dx;
        float pd = len;
        if (pd > 0.0f) { px /= pd; py /= pd; }
        px *= w * 0.5f; py *= w * 0.5f;
        float right = fmaxf(fmaxf(sx + px, sx - px), fmaxf(ex + px, ex - px));
        float top   = fmaxf(fmaxf(sy + py, sy - py), fmaxf(ey + py, ey - py));
        float bbw = fabsf((right - cx) * 2.0f);
        float bbh = fabsf((top   - cy) * 2.0f);
        float bba = bbw * bbh;
        float ar  = (bba > 0.001f) ? (area / bba) : 1.0f;

        float* f = (lane < NW) ? featT[lane] : featP[lane - NW];
        f[0] = cx;  f[1] = cy;  f[2] = area; f[3] = sr;
        f[4] = ar;  f[5] = bbw; f[6] = bbh;  f[7] = prob;
    }
    if (lane < NW) rw[lane] = 64;           // CR winner init
    __syncthreads();

    // ------- Phase 2: 32x32 cost matrix + fused column-min (CR part 1) --------
    float cmin = BIGF; int cargmin = 0;
    for (int e = lane; e < NW * NW; e += 64) {
        int i = e >> 5, j = e & 31;
        float dcx = featT[i][0] - featP[j][0];
        float dcy = featT[i][1] - featP[j][1];
        float center_d = dcx * dcx + dcy * dcy;
        float da = featT[i][2] - featP[j][2];   float area_d  = da * da;
        float ds = featT[i][3] - featP[j][3];   float lwr_d   = ds * ds;
        float dr = featT[i][4] - featP[j][4];   float rot_d   = dr * dr;
        float dxw = featT[i][5] - featP[j][5];  float horiz_d = dxw * dxw;
        float dyh = featT[i][6] - featP[j][6];  float vert_d  = dyh * dyh;
        float probt = featT[i][7], probp = featP[j][7];
        float dp = probt - probp;               float prob_d  = dp * dp;
        float param_d = area_d + center_d + rot_d + horiz_d + vert_d + lwr_d;
        float val = 10.0f * prob_d + param_d * probt;
        cost[i][j] = val;
        if (val < cmin) { cmin = val; cargmin = i; }   // rows ascending: first-min
    }
    {
        float om = __shfl_xor(cmin, 32);
        int   oi = __shfl_xor(cargmin, 32);
        if (om < cmin || (om == cmin && oi < cargmin)) { cmin = om; cargmin = oi; }
    }
    __syncthreads();

    // --------- CR part 2: deterministic unique-argmin greedy assignment --------
    if (lane < NW) atomicMin(&rw[cargmin], lane);
    __syncthreads();

    const bool isCol = lane < NW;
    const int  col   = lane & 31;
    float v_col   = isCol ? cmin : 0.0f;    // v = column min (feasible duals)
    float u_row   = 0.0f;
    int   win     = isCol ? rw[lane] : 64;
    int   col4row = (isCol && win < 64) ? win : -1;
    int   row4col = (isCol && rw[cargmin] == lane) ? cargmin : -1;
    __syncthreads();

    unsigned rem      = (unsigned)(__ballot(isCol && col4row < 0) & 0xffffffffull);
    unsigned freeCols = (unsigned)(__ballot(isCol && row4col < 0) & 0xffffffffull);

    // ------- Greedy free-row pass (ART-lite): u_i = min slack; assign if -------
    // the argmin column is free (edge tight, duals stay feasible).
    {
        unsigned g = rem;
        while (g != 0) {
            int i = __ffs(g) - 1;
            g &= (g - 1);
            float cij = cost[i][col];
            float slack = cij - v_col;                     // >= 0 (v = colmin)
            unsigned key = isCol
                ? ((__float_as_uint(slack) & 0xFFFFFFE0u) | (unsigned)col)
                : 0xFFFFFFFFu;
            unsigned kmin = wave_umin32_key(key);
            int   j1 = (int)(kmin & 31u);
            float m1 = __uint_as_float(kmin & 0xFFFFFFE0u);
            if (lane == i) u_row = m1;                     // tighten dual (feasible)
            if ((freeCols >> j1) & 1u) {                   // assign only if free
                if (lane == j1) row4col = i;
                if (lane == i)  col4row = j1;
                freeCols &= ~(1u << j1);
                rem      &= ~(1u << i);
            }
        }
    }

    // ---------------- SAP: shortest augmenting path for leftover rows ----------
    {
        while (rem != 0) {
            int i0 = __ffs(rem) - 1;
            rem &= (rem - 1);

            bool     SCb     = !isCol;
            unsigned spcKey  = 0xFFFFFFFFu;    // (quantized slack | j), frozen at SC
            int      pathReg = 0;
            unsigned srMask  = 1u << i0;
            unsigned minBits = 0u;             // quantized minVal bits (+0.0f)
            int      i = i0;
            int      sink;

            float cij    = cost[i][col];                   // prefetched cost row
            float sDelta = 0.0f - readlane_f(u_row, i);    // minVal(0) - u[i0]
            while (true) {
                // slack = (cij - v_col) + (minVal - u_i); clamp >=0 so the bit
                // pattern is order-monotone for the packed-key u32 min.
                float slack = fmaxf((cij - v_col) + sDelta, 0.0f);
                unsigned key = (__float_as_uint(slack) & 0xFFFFFFE0u) | (unsigned)col;
                unsigned old = spcKey;
                unsigned mn  = key < spcKey ? key : spcKey;
                spcKey = SCb ? spcKey : mn;                    // freeze when SC
                pathReg = (spcKey != old) ? i : pathReg;       // source row of best

                // Tight-edge fast path: any unscanned column with spc == minVal
                // is an argmin (Dijkstra distances are monotone), skip reduction.
                unsigned long long tight =
                    __ballot(!SCb && (spcKey & 0xFFFFFFE0u) == minBits);
                int j;
                if (tight) {
                    j = __ffsll(tight) - 1;                    // minBits unchanged
                } else {
                    unsigned red = SCb ? 0xFFFFFFFFu : spcKey;
                    red = dpp_umin_step<0x111>(red);           // row_shr:1
                    red = dpp_umin_step<0x112>(red);           // row_shr:2
                    red = dpp_umin_step<0x114>(red);           // row_shr:4
                    red = dpp_umin_step<0x118>(red);           // row_shr:8
                    unsigned kA = (unsigned)__builtin_amdgcn_readlane((int)red, 15);
                    unsigned kB = (unsigned)__builtin_amdgcn_readlane((int)red, 31);
                    unsigned kmin = kA < kB ? kA : kB;         // scalar merge
                    j = (int)(kmin & 31u);
                    minBits = kmin & 0xFFFFFFE0u;
                }
                SCb = SCb || (lane == j);
                int r = __builtin_amdgcn_readlane(row4col, j);
                if ((freeCols >> j) & 1u) { sink = j; break; }
                i = r;
                srMask |= (1u << i);
                cij = cost[i][col];                            // issue ASAP
                float u_i = readlane_f(u_row, i);              // off-chain tail
                sDelta = __uint_as_float(minBits) - u_i;
            }

            // dual updates (spc recovered from frozen keys, quantized)
            {
                float minValF = __uint_as_float(minBits);
                float spcF = __uint_as_float(spcKey & 0xFFFFFFE0u);
                int gidx = (col4row < 0) ? 0 : col4row;
                float spc_at_c4r = __shfl(spcF, gidx);
                bool in_SR = isCol && ((srMask >> col) & 1u);
                if (lane == i0)              u_row += minValF;
                else if (in_SR)              u_row += minValF - spc_at_c4r;
                if (isCol && SCb)            v_col -= (minValF - spcF);
            }

            // augment along path
            {
                int j = sink;
                freeCols &= ~(1u << sink);
                while (true) {
                    int ii = __builtin_amdgcn_readlane(pathReg, j);
                    if (lane == j) row4col = ii;
                    int j_next = __builtin_amdgcn_readlane(col4row, ii);
                    if (lane == ii) col4row = j;
                    if (ii == i0) break;
                    j = j_next;
                }
            }
        }
    }

    // ---------------- Loss = sum of assigned edge costs ------------------------
    float myedge = (isCol && col4row >= 0) ? cost[lane][col4row] : 0.0f;
    #pragma unroll
    for (int off = 32; off >= 1; off >>= 1)
        myedge += __shfl_xor(myedge, off);
    if (lane == 0) out[b] = myedge;
}

extern "C" void kernel_launch(void* const* d_in, const int* in_sizes, int n_in,
                              void* d_out, int out_size, void* d_ws, size_t ws_size,
                              hipStream_t stream) {
    const float* params_true = (const float*)d_in[0];
    const float* params_pred = (const float*)d_in[1];
    float* out = (float*)d_out;
    floorplan_hungarian_kernel<<<BATCH, 64, 0, stream>>>(params_true, params_pred, out);
}

// Round 14
// 115.462 us; speedup vs baseline: 1.1279x; 1.0389x over previous
//
#include <hip/hip_runtime.h>

#define NW 32
#define BATCH 2048
#define BIGF 1e9f

// One DPP u32-min step (row_shr within 16-lane rows). bound_ctrl=false:
// invalid-source lanes keep old value = min identity.
template <int CTRL>
__device__ __forceinline__ unsigned dpp_umin_step(unsigned x) {
    unsigned t = (unsigned)__builtin_amdgcn_update_dpp((int)x, (int)x, CTRL, 0xF, 0xF, false);
    return t < x ? t : x;
}

// Packed-key min over lanes 0..31 (others must hold ~0u): 4 DPP row_shr steps
// leave min(0..15) at lane 15, min(16..31) at lane 31; merge as scalars.
__device__ __forceinline__ unsigned wave_umin32_key(unsigned red) {
    red = dpp_umin_step<0x111>(red);   // row_shr:1
    red = dpp_umin_step<0x112>(red);   // row_shr:2
    red = dpp_umin_step<0x114>(red);   // row_shr:4
    red = dpp_umin_step<0x118>(red);   // row_shr:8
    unsigned kA = (unsigned)__builtin_amdgcn_readlane((int)red, 15);
    unsigned kB = (unsigned)__builtin_amdgcn_readlane((int)red, 31);
    return kA < kB ? kA : kB;
}

__device__ __forceinline__ float readlane_f(float v, int lane) {
    return __int_as_float(__builtin_amdgcn_readlane(__float_as_int(v), lane));
}

__global__ __launch_bounds__(64) void floorplan_hungarian_kernel(
    const float* __restrict__ params_true,
    const float* __restrict__ params_pred,
    float* __restrict__ out)
{
    const int b    = blockIdx.x;
    const int lane = threadIdx.x;           // 0..63, one full wave

    __shared__ float cost[NW][NW + 1];      // padded rows: conflict-free
    __shared__ float featT[NW][9];
    __shared__ float featP[NW][9];
    __shared__ int   rw[NW];                // CR: winning column per row

    // ---------------- Phase 1: per-wall features (1 wall per lane) -------------
    {
        const float* src = (lane < NW)
            ? (params_true + ((size_t)b * NW + lane) * 6)
            : (params_pred + ((size_t)b * NW + (lane - NW)) * 6);
        float sx = src[0], sy = src[1], ex = src[2], ey = src[3];
        float w  = src[4], prob = src[5];

        float dx = ex - sx, dy = ey - sy;
        float cx = (sx + ex) * 0.5f, cy = (sy + ey) * 0.5f;
        float len = sqrtf(dx * dx + dy * dy);
        float area = len * w;

        float smaller = fminf(w, len), bigger = fmaxf(w, len);
        float sr = (bigger > 0.0f) ? (smaller / bigger) : 0.0f;

        float px = dy, py = -dx;
        float pd = len;
        if (pd > 0.0f) { px /= pd; py /= pd; }
        px *= w * 0.5f; py *= w * 0.5f;
        float right = fmaxf(fmaxf(sx + px, sx - px), fmaxf(ex + px, ex - px));
        float top   = fmaxf(fmaxf(sy + py, sy - py), fmaxf(ey + py, ey - py));
        float bbw = fabsf((right - cx) * 2.0f);
        float bbh = fabsf((top   - cy) * 2.0f);
        float bba = bbw * bbh;
        float ar  = (bba > 0.001f) ? (area / bba) : 1.0f;

        float* f = (lane < NW) ? featT[lane] : featP[lane - NW];
        f[0] = cx;  f[1] = cy;  f[2] = area; f[3] = sr;
        f[4] = ar;  f[5] = bbw; f[6] = bbh;  f[7] = prob;
    }
    if (lane < NW) rw[lane] = 64;           // CR winner init
    __syncthreads();

    // ------- Phase 2: 32x32 cost matrix + fused column-min (CR part 1) --------
    float cmin = BIGF; int cargmin = 0;
    for (int e = lane; e < NW * NW; e += 64) {
        int i = e >> 5, j = e & 31;
        float dcx = featT[i][0] - featP[j][0];
        float dcy = featT[i][1] - featP[j][1];
        float center_d = dcx * dcx + dcy * dcy;
        float da = featT[i][2] - featP[j][2];   float area_d  = da * da;
        float ds = featT[i][3] - featP[j][3];   float lwr_d   = ds * ds;
        float dr = featT[i][4] - featP[j][4];   float rot_d   = dr * dr;
        float dxw = featT[i][5] - featP[j][5];  float horiz_d = dxw * dxw;
        float dyh = featT[i][6] - featP[j][6];  float vert_d  = dyh * dyh;
        float probt = featT[i][7], probp = featP[j][7];
        float dp = probt - probp;               float prob_d  = dp * dp;
        float param_d = area_d + center_d + rot_d + horiz_d + vert_d + lwr_d;
        float val = 10.0f * prob_d + param_d * probt;
        cost[i][j] = val;
        if (val < cmin) { cmin = val; cargmin = i; }   // rows ascending: first-min
    }
    {
        float om = __shfl_xor(cmin, 32);
        int   oi = __shfl_xor(cargmin, 32);
        if (om < cmin || (om == cmin && oi < cargmin)) { cmin = om; cargmin = oi; }
    }
    __syncthreads();

    // --------- CR part 2: deterministic unique-argmin greedy assignment --------
    if (lane < NW) atomicMin(&rw[cargmin], lane);
    __syncthreads();

    const bool isCol = lane < NW;
    const int  col   = lane & 31;
    float v_col   = isCol ? cmin : 0.0f;    // v = column min (feasible duals)
    float u_row   = 0.0f;
    int   win     = isCol ? rw[lane] : 64;
    int   col4row = (isCol && win < 64) ? win : -1;
    int   row4col = (isCol && rw[cargmin] == lane) ? cargmin : -1;
    __syncthreads();

    unsigned rem      = (unsigned)(__ballot(isCol && col4row < 0) & 0xffffffffull);
    unsigned freeCols = (unsigned)(__ballot(isCol && row4col < 0) & 0xffffffffull);

    // ------- Greedy free-row pass (ART-lite): u_i = min slack; assign if -------
    // the argmin column is free (edge tight, duals stay feasible). Key bit 5 =
    // "column assigned": among quantized-equal slacks, free columns win.
    {
        unsigned g = rem;
        while (g != 0) {
            int i = __ffs(g) - 1;
            g &= (g - 1);
            unsigned gtag = (((freeCols >> col) & 1u) ? 0u : 32u) | (unsigned)col;
            float cij = cost[i][col];
            float slack = cij - v_col;                     // >= 0 (v = colmin)
            unsigned key = isCol
                ? ((__float_as_uint(slack) & 0xFFFFFFC0u) | gtag)
                : 0xFFFFFFFFu;
            unsigned kmin = wave_umin32_key(key);
            int   j1 = (int)(kmin & 31u);
            float m1 = __uint_as_float(kmin & 0xFFFFFFC0u);
            if (lane == i) u_row = m1;                     // tighten dual (feasible)
            if ((freeCols >> j1) & 1u) {                   // assign only if free
                if (lane == j1) row4col = i;
                if (lane == i)  col4row = j1;
                freeCols &= ~(1u << j1);
                rem      &= ~(1u << i);
            }
        }
    }

    // ---------------- SAP: shortest augmenting path for leftover rows ----------
    {
        while (rem != 0) {
            int i0 = __ffs(rem) - 1;
            rem &= (rem - 1);

            bool     SCb     = !isCol;
            unsigned spcKey  = 0xFFFFFFFFu;    // (quantized slack | tag), frozen at SC
            int      pathReg = 0;
            unsigned srMask  = 1u << i0;
            float    minValF = 0.0f;
            int      i = i0;
            int      sink;

            // tag constant during one Dijkstra: bit5 = column assigned.
            unsigned tag = (((freeCols >> col) & 1u) ? 0u : 32u) | (unsigned)col;

            float cij = cost[i][col];          // prefetched cost row
            while (true) {
                float u_i = readlane_f(u_row, i);              // || with ds_read
                float t   = (minValF - v_col) - u_i;           // || with ds_read
                float slack = fmaxf(t + cij, 0.0f);            // >=0: bits monotone
                unsigned key = (__float_as_uint(slack) & 0xFFFFFFC0u) | tag;
                unsigned old = spcKey;
                unsigned mn  = key < spcKey ? key : spcKey;
                spcKey = SCb ? spcKey : mn;                    // freeze when SC
                pathReg = (spcKey != old) ? i : pathReg;       // source row of best
                unsigned red = SCb ? 0xFFFFFFFFu : spcKey;

                unsigned kmin = wave_umin32_key(red);
                int j = (int)(kmin & 31u);                     // index in low bits
                minValF = __uint_as_float(kmin & 0xFFFFFFC0u); // value, quantized
                SCb = SCb || (lane == j);
                int r = __builtin_amdgcn_readlane(row4col, j); // || with bit test
                if ((freeCols >> j) & 1u) { sink = j; break; }
                i = r;
                srMask |= (1u << i);
                cij = cost[i][col];                            // prefetch next row
            }

            // dual updates (spc recovered from frozen keys, quantized)
            {
                float spcF = __uint_as_float(spcKey & 0xFFFFFFC0u);
                int gidx = (col4row < 0) ? 0 : col4row;
                float spc_at_c4r = __shfl(spcF, gidx);
                bool in_SR = isCol && ((srMask >> col) & 1u);
                if (lane == i0)              u_row += minValF;
                else if (in_SR)              u_row += minValF - spc_at_c4r;
                if (isCol && SCb)            v_col -= (minValF - spcF);
            }

            // augment along path
            {
                int j = sink;
                freeCols &= ~(1u << sink);
                while (true) {
                    int ii = __builtin_amdgcn_readlane(pathReg, j);
                    if (lane == j) row4col = ii;
                    int j_next = __builtin_amdgcn_readlane(col4row, ii);
                    if (lane == ii) col4row = j;
                    if (ii == i0) break;
                    j = j_next;
                }
            }
        }
    }

    // ---------------- Loss = sum of assigned edge costs ------------------------
    float myedge = (isCol && col4row >= 0) ? cost[lane][col4row] : 0.0f;
    #pragma unroll
    for (int off = 32; off >= 1; off >>= 1)
        myedge += __shfl_xor(myedge, off);
    if (lane == 0) out[b] = myedge;
}

extern "C" void kernel_launch(void* const* d_in, const int* in_sizes, int n_in,
                              void* d_out, int out_size, void* d_ws, size_t ws_size,
                              hipStream_t stream) {
    const float* params_true = (const float*)d_in[0];
    const float* params_pred = (const float*)d_in[1];
    float* out = (float*)d_out;
    floorplan_hungarian_kernel<<<BATCH, 64, 0, stream>>>(params_true, params_pred, out);
}

// Round 15
// 113.084 us; speedup vs baseline: 1.1516x; 1.0210x over previous
//
#include <hip/hip_runtime.h>

#define NW 32
#define BATCH 2048
#define BIGF 1e9f

// One DPP u32-min step (row_shr within 16-lane rows). bound_ctrl=false:
// invalid-source lanes keep old value = min identity.
template <int CTRL>
__device__ __forceinline__ unsigned dpp_umin_step(unsigned x) {
    unsigned t = (unsigned)__builtin_amdgcn_update_dpp((int)x, (int)x, CTRL, 0xF, 0xF, false);
    return t < x ? t : x;
}

// Packed-key min over lanes 0..31 (others must hold ~0u): 4 DPP row_shr steps
// leave min(0..15) at lane 15, min(16..31) at lane 31; merge as scalars.
__device__ __forceinline__ unsigned wave_umin32_key(unsigned red) {
    red = dpp_umin_step<0x111>(red);   // row_shr:1
    red = dpp_umin_step<0x112>(red);   // row_shr:2
    red = dpp_umin_step<0x114>(red);   // row_shr:4
    red = dpp_umin_step<0x118>(red);   // row_shr:8
    unsigned kA = (unsigned)__builtin_amdgcn_readlane((int)red, 15);
    unsigned kB = (unsigned)__builtin_amdgcn_readlane((int)red, 31);
    return kA < kB ? kA : kB;
}

__device__ __forceinline__ float readlane_f(float v, int lane) {
    return __int_as_float(__builtin_amdgcn_readlane(__float_as_int(v), lane));
}

__global__ __launch_bounds__(64) void floorplan_hungarian_kernel(
    const float* __restrict__ params_true,
    const float* __restrict__ params_pred,
    float* __restrict__ out)
{
    const int b    = blockIdx.x;
    const int lane = threadIdx.x;           // 0..63, one full wave

    __shared__ float cost[NW][NW + 1];      // padded rows: conflict-free
    __shared__ float featT[NW][9];
    __shared__ float featP[NW][9];
    __shared__ int   rw[NW];                // CR: winning column per row

    // ---------------- Phase 1: per-wall features (1 wall per lane) -------------
    {
        const float* src = (lane < NW)
            ? (params_true + ((size_t)b * NW + lane) * 6)
            : (params_pred + ((size_t)b * NW + (lane - NW)) * 6);
        float sx = src[0], sy = src[1], ex = src[2], ey = src[3];
        float w  = src[4], prob = src[5];

        float dx = ex - sx, dy = ey - sy;
        float cx = (sx + ex) * 0.5f, cy = (sy + ey) * 0.5f;
        float len = sqrtf(dx * dx + dy * dy);
        float area = len * w;

        float smaller = fminf(w, len), bigger = fmaxf(w, len);
        float sr = (bigger > 0.0f) ? (smaller / bigger) : 0.0f;

        float px = dy, py = -dx;
        float pd = len;
        if (pd > 0.0f) { px /= pd; py /= pd; }
        px *= w * 0.5f; py *= w * 0.5f;
        float right = fmaxf(fmaxf(sx + px, sx - px), fmaxf(ex + px, ex - px));
        float top   = fmaxf(fmaxf(sy + py, sy - py), fmaxf(ey + py, ey - py));
        float bbw = fabsf((right - cx) * 2.0f);
        float bbh = fabsf((top   - cy) * 2.0f);
        float bba = bbw * bbh;
        float ar  = (bba > 0.001f) ? (area / bba) : 1.0f;

        float* f = (lane < NW) ? featT[lane] : featP[lane - NW];
        f[0] = cx;  f[1] = cy;  f[2] = area; f[3] = sr;
        f[4] = ar;  f[5] = bbw; f[6] = bbh;  f[7] = prob;
    }
    if (lane < NW) rw[lane] = 64;           // CR winner init
    __syncthreads();

    // ------- Phase 2: 32x32 cost matrix + fused column-min (CR part 1) --------
    float cmin = BIGF; int cargmin = 0;
    for (int e = lane; e < NW * NW; e += 64) {
        int i = e >> 5, j = e & 31;
        float dcx = featT[i][0] - featP[j][0];
        float dcy = featT[i][1] - featP[j][1];
        float center_d = dcx * dcx + dcy * dcy;
        float da = featT[i][2] - featP[j][2];   float area_d  = da * da;
        float ds = featT[i][3] - featP[j][3];   float lwr_d   = ds * ds;
        float dr = featT[i][4] - featP[j][4];   float rot_d   = dr * dr;
        float dxw = featT[i][5] - featP[j][5];  float horiz_d = dxw * dxw;
        float dyh = featT[i][6] - featP[j][6];  float vert_d  = dyh * dyh;
        float probt = featT[i][7], probp = featP[j][7];
        float dp = probt - probp;               float prob_d  = dp * dp;
        float param_d = area_d + center_d + rot_d + horiz_d + vert_d + lwr_d;
        float val = 10.0f * prob_d + param_d * probt;
        cost[i][j] = val;
        if (val < cmin) { cmin = val; cargmin = i; }   // rows ascending: first-min
    }
    {
        float om = __shfl_xor(cmin, 32);
        int   oi = __shfl_xor(cargmin, 32);
        if (om < cmin || (om == cmin && oi < cargmin)) { cmin = om; cargmin = oi; }
    }
    __syncthreads();

    // --------- CR part 2: deterministic unique-argmin greedy assignment --------
    if (lane < NW) atomicMin(&rw[cargmin], lane);
    __syncthreads();

    const bool isCol = lane < NW;
    const int  col   = lane & 31;
    float v_col   = isCol ? cmin : 0.0f;    // v = column min (feasible duals)
    float u_row   = 0.0f;
    int   win     = isCol ? rw[lane] : 64;
    int   col4row = (isCol && win < 64) ? win : -1;
    int   row4col = (isCol && rw[cargmin] == lane) ? cargmin : -1;
    __syncthreads();

    unsigned rem      = (unsigned)(__ballot(isCol && col4row < 0) & 0xffffffffull);
    unsigned freeCols = (unsigned)(__ballot(isCol && row4col < 0) & 0xffffffffull);

    // ------- Greedy free-row pass (ART-lite): u_i = min slack; assign if -------
    // the argmin column is free (edge tight, duals stay feasible).
    {
        unsigned g = rem;
        while (g != 0) {
            int i = __ffs(g) - 1;
            g &= (g - 1);
            float cij = cost[i][col];
            float slack = cij - v_col;                     // >= 0 (v = colmin)
            unsigned key = isCol
                ? ((__float_as_uint(slack) & 0xFFFFFFE0u) | (unsigned)col)
                : 0xFFFFFFFFu;
            unsigned kmin = wave_umin32_key(key);
            int   j1 = (int)(kmin & 31u);
            float m1 = __uint_as_float(kmin & 0xFFFFFFE0u);
            if (lane == i) u_row = m1;                     // tighten dual (feasible)
            if ((freeCols >> j1) & 1u) {                   // assign only if free
                if (lane == j1) row4col = i;
                if (lane == i)  col4row = j1;
                freeCols &= ~(1u << j1);
                rem      &= ~(1u << i);
            }
        }
    }

    // ---------------- SAP: shortest augmenting path for leftover rows ----------
    {
        while (rem != 0) {
            int i0 = __ffs(rem) - 1;
            rem &= (rem - 1);

            bool     SCb     = !isCol;
            unsigned spcKey  = 0xFFFFFFFFu;    // (quantized slack | j), frozen at SC
            int      pathReg = 0;
            unsigned srMask  = 1u << i0;
            float    minValF = 0.0f;
            int      i = i0;
            int      sink;

            float cij = cost[i][col];          // prefetched cost row
            while (true) {
                float u_i = readlane_f(u_row, i);              // || with ds_read
                float t   = (minValF - v_col) - u_i;           // || with ds_read
                float slack = fmaxf(t + cij, 0.0f);            // >=0: bits monotone
                unsigned key = (__float_as_uint(slack) & 0xFFFFFFE0u) | (unsigned)col;
                unsigned old = spcKey;
                unsigned mn  = key < spcKey ? key : spcKey;
                spcKey = SCb ? spcKey : mn;                    // freeze when SC
                pathReg = (spcKey != old) ? i : pathReg;       // source row of best
                unsigned red = SCb ? 0xFFFFFFFFu : spcKey;

                unsigned kmin = wave_umin32_key(red);
                int j = (int)(kmin & 31u);                     // index in low bits
                minValF = __uint_as_float(kmin & 0xFFFFFFE0u); // value, quantized
                SCb = SCb || (lane == j);
                int r = __builtin_amdgcn_readlane(row4col, j); // || with bit test
                if ((freeCols >> j) & 1u) { sink = j; break; }
                i = r;
                srMask |= (1u << i);
                cij = cost[i][col];                            // prefetch next row
            }

            // dual updates (spc recovered from frozen keys, quantized)
            {
                float spcF = __uint_as_float(spcKey & 0xFFFFFFE0u);
                int gidx = (col4row < 0) ? 0 : col4row;
                float spc_at_c4r = __shfl(spcF, gidx);
                bool in_SR = isCol && ((srMask >> col) & 1u);
                if (lane == i0)              u_row += minValF;
                else if (in_SR)              u_row += minValF - spc_at_c4r;
                if (isCol && SCb)            v_col -= (minValF - spcF);
            }

            // augment along path
            {
                int j = sink;
                freeCols &= ~(1u << sink);
                while (true) {
                    int ii = __builtin_amdgcn_readlane(pathReg, j);
                    if (lane == j) row4col = ii;
                    int j_next = __builtin_amdgcn_readlane(col4row, ii);
                    if (lane == ii) col4row = j;
                    if (ii == i0) break;
                    j = j_next;
                }
            }
        }
    }

    // ---------------- Loss = sum of assigned edge costs ------------------------
    float myedge = (isCol && col4row >= 0) ? cost[lane][col4row] : 0.0f;
    #pragma unroll
    for (int off = 32; off >= 1; off >>= 1)
        myedge += __shfl_xor(myedge, off);
    if (lane == 0) out[b] = myedge;
}

extern "C" void kernel_launch(void* const* d_in, const int* in_sizes, int n_in,
                              void* d_out, int out_size, void* d_ws, size_t ws_size,
                              hipStream_t stream) {
    const float* params_true = (const float*)d_in[0];
    const float* params_pred = (const float*)d_in[1];
    float* out = (float*)d_out;
    floorplan_hungarian_kernel<<<BATCH, 64, 0, stream>>>(params_true, params_pred, out);
}